// Round 9
// baseline (125.039 us; speedup 1.0000x reference)
//
#include <hip/hip_runtime.h>
#include <cstddef>
#include <cstdint>

#define POS_LEN    32768
#define NUM_NEG    64
#define N_RULES    262144
#define N_UNLABEL  131072
#define NUM_ENT    100000
#define NUM_REL    500
#define EMB_DIM    256
#define WEIGHT_DECAY 1e-5

#define AUX_BLOCKS    2048
#define GATHER_BLOCKS 2048
#define LOSS_BLOCKS   1024

typedef __attribute__((ext_vector_type(2))) float        f32x2;
typedef __attribute__((ext_vector_type(4))) float        f32x4;
typedef __attribute__((ext_vector_type(2))) unsigned int u32x2;
typedef __attribute__((ext_vector_type(4))) unsigned int u32x4;

__device__ __forceinline__ float softplusf_(float x) {
    return fmaxf(x, 0.0f) + log1pf(expf(-fabsf(x)));
}
__device__ __forceinline__ float sigmoidf_(float x) {
    return 1.0f / (1.0f + expf(-x));
}
__device__ __forceinline__ float quarter_sum16(float v) {   // reduce within 16-lane group
#pragma unroll
    for (int m = 1; m <= 8; m <<= 1) v += __shfl_xor(v, m, 64);
    return v;
}
__device__ __forceinline__ float wave_sum64(float v) {
#pragma unroll
    for (int m = 32; m >= 1; m >>= 1) v += __shfl_xor(v, m, 64);
    return v;
}
__device__ __forceinline__ double wave_sum64d(double v) {
#pragma unroll
    for (int m = 32; m >= 1; m >>= 1) v += __shfl_xor(v, m, 64);
    return v;
}

// ---- fp8 (OCP e4m3) pack/unpack via gfx950 HW converts (proven R4/R7) ----
__device__ __forceinline__ u32x2 f32x8_to_fp8(const f32x4 a, const f32x4 b) {
    int lo = 0, hi = 0;
    lo = __builtin_amdgcn_cvt_pk_fp8_f32(a[0], a[1], lo, false);
    lo = __builtin_amdgcn_cvt_pk_fp8_f32(a[2], a[3], lo, true);
    hi = __builtin_amdgcn_cvt_pk_fp8_f32(b[0], b[1], hi, false);
    hi = __builtin_amdgcn_cvt_pk_fp8_f32(b[2], b[3], hi, true);
    u32x2 r; r[0] = (unsigned)lo; r[1] = (unsigned)hi; return r;
}

// Quarter-wave tri-product over 16 fp8 elems/lane (16 lanes x 16 = 256 dims).
// float2-packed: compiler emits v_pk_mul_f32 / v_pk_fma_f32 (half the element insts).
__device__ __forceinline__ float dot3_q(const u32x4 hv, const u32x4 rv, const u32x4 tv) {
    f32x2 acc = {0.0f, 0.0f};
#pragma unroll
    for (int w = 0; w < 4; ++w) {
        f32x2 h0 = __builtin_amdgcn_cvt_pk_f32_fp8((int)hv[w], false);
        f32x2 h1 = __builtin_amdgcn_cvt_pk_f32_fp8((int)hv[w], true);
        f32x2 r0 = __builtin_amdgcn_cvt_pk_f32_fp8((int)rv[w], false);
        f32x2 r1 = __builtin_amdgcn_cvt_pk_f32_fp8((int)rv[w], true);
        f32x2 t0 = __builtin_amdgcn_cvt_pk_f32_fp8((int)tv[w], false);
        f32x2 t1 = __builtin_amdgcn_cvt_pk_f32_fp8((int)tv[w], true);
        acc += (h0 * r0) * t0;
        acc += (h1 * r1) * t1;
    }
    return quarter_sum16(acc[0] + acc[1]);
}

// ---- Kernel 1: quantize ent/rel -> fp8, f32 sum-of-squares, zero pi_grad
//      and the loss completion counter. Per-block partials, no atomics. ----
__global__ __launch_bounds__(256) void aux_fp8_kernel(const float* __restrict__ ent,
                                                      const float* __restrict__ rel,
                                                      u32x2* __restrict__ ent8,
                                                      u32x2* __restrict__ rel8,
                                                      float* __restrict__ pi_grad,
                                                      float* __restrict__ auxp,
                                                      unsigned* __restrict__ done_count) {
    const int tid = blockIdx.x * blockDim.x + threadIdx.x;
    const int stride = gridDim.x * blockDim.x;
    if (tid == 0) *done_count = 0u;
    for (int i = tid; i < N_UNLABEL; i += stride) pi_grad[i] = 0.0f;

    float sq = 0.0f;
    const f32x4* entv = reinterpret_cast<const f32x4*>(ent);
    for (int i = tid; i < (NUM_ENT * EMB_DIM) / 8; i += stride) {
        f32x4 a = __builtin_nontemporal_load(entv + (size_t)i * 2);
        f32x4 b = __builtin_nontemporal_load(entv + (size_t)i * 2 + 1);
        sq += a[0]*a[0] + a[1]*a[1] + a[2]*a[2] + a[3]*a[3]
            + b[0]*b[0] + b[1]*b[1] + b[2]*b[2] + b[3]*b[3];
        ent8[i] = f32x8_to_fp8(a, b);
    }
    const f32x4* relv = reinterpret_cast<const f32x4*>(rel);
    for (int i = tid; i < (NUM_REL * EMB_DIM) / 8; i += stride) {
        f32x4 a = __builtin_nontemporal_load(relv + (size_t)i * 2);
        f32x4 b = __builtin_nontemporal_load(relv + (size_t)i * 2 + 1);
        sq += a[0]*a[0] + a[1]*a[1] + a[2]*a[2] + a[3]*a[3]
            + b[0]*b[0] + b[1]*b[1] + b[2]*b[2] + b[3]*b[3];
        rel8[i] = f32x8_to_fp8(a, b);
    }
    sq = wave_sum64(sq);
    __shared__ float ls[8];
    const int lane = threadIdx.x & 63, wid = threadIdx.x >> 6;
    if (lane == 0) ls[wid] = sq;
    __syncthreads();
    if (threadIdx.x == 0) {
        float bs = 0.0f;
        for (int w = 0; w < (int)(blockDim.x >> 6); ++w) bs += ls[w];
        auxp[blockIdx.x] = bs;
    }
}

// ---- Kernel 2: fused fp8 gathers, quarter-wave (4 triples/wave), R7 structure.
// All row loads (p1 + predicated p2) issued before any convert math. ----
__global__ void gather_kernel(const float* __restrict__ conf,
                              const u32x4* __restrict__ ent8,
                              const u32x4* __restrict__ rel8,
                              const int* __restrict__ p1,
                              const int* __restrict__ p2,
                              const int* __restrict__ tnum,
                              const int* __restrict__ uids,
                              const int* __restrict__ ut,
                              float* __restrict__ pi_grad,
                              float* __restrict__ su_out) {
    const int lane = threadIdx.x & 63;
    const int l    = lane & 15;
    const int q    = lane >> 4;   // quarter 0..3
    const int wave  = blockIdx.x * (blockDim.x >> 6) + (threadIdx.x >> 6);
    const int nwave = gridDim.x * (blockDim.x >> 6);
    const int nr4 = N_RULES / 4, nu4 = N_UNLABEL / 4, ntot = nr4 + nu4;

    for (int pi = wave; pi < ntot; pi += nwave) {
        if (pi < nr4) {
            const int rule = pi * 4 + q;
            const int b = rule * 3;
            const int h1 = p1[b], r1 = p1[b + 1], t1 = p1[b + 2];
            const int tn = tnum[rule];
            const float cf = conf[rule];
            const int uid = uids[rule];
            const bool has2 = (tn == 3);
            // issue ALL row loads up front
            const u32x4 H1 = ent8[(size_t)h1 * 16 + l];
            const u32x4 R1 = rel8[(size_t)r1 * 16 + l];
            const u32x4 T1 = ent8[(size_t)t1 * 16 + l];
            u32x4 H2 = {0, 0, 0, 0}, R2 = {0, 0, 0, 0}, T2 = {0, 0, 0, 0};
            if (has2) {
                const int h2 = p2[b], r2 = p2[b + 1], t2 = p2[b + 2];
                H2 = ent8[(size_t)h2 * 16 + l];
                R2 = rel8[(size_t)r2 * 16 + l];
                T2 = ent8[(size_t)t2 * 16 + l];
            }
            float c = sigmoidf_(dot3_q(H1, R1, T1)) * cf;
            if (has2) c *= sigmoidf_(dot3_q(H2, R2, T2));
            if (l == 0) atomicAdd(&pi_grad[uid], c);
        } else {
            const int i = (pi - nr4) * 4 + q;
            const int b = i * 3;
            const int h = ut[b], r = ut[b + 1], t = ut[b + 2];
            const u32x4 H = ent8[(size_t)h * 16 + l];
            const u32x4 R = rel8[(size_t)r * 16 + l];
            const u32x4 T = ent8[(size_t)t * 16 + l];
            const float su = dot3_q(H, R, T);
            if (l == 0) su_out[i] = su;
        }
    }
}

// ---- Kernel 3: unlabel loss + pos/neg softplus sums. Per-block partials;
//      the LAST block to finish performs the final f64 reduction (saves a
//      dispatch). Deterministic: one block sums fixed partials in fixed order. ----
__global__ __launch_bounds__(256) void loss_kernel(const float* __restrict__ su,
                                                   const float* __restrict__ pi_grad,
                                                   const float* __restrict__ pos,
                                                   const float* __restrict__ neg,
                                                   const float* __restrict__ auxp,
                                                   float* __restrict__ lossp,
                                                   unsigned* __restrict__ done_count,
                                                   float* __restrict__ out) {
    const int tid = blockIdx.x * blockDim.x + threadIdx.x;
    const int stride = gridDim.x * blockDim.x;
    float ul = 0.0f, ps = 0.0f, ns = 0.0f;
    for (int i = tid; i < N_UNLABEL; i += stride) {
        const float s   = su[i];
        const float p   = sigmoidf_(s);
        const float tgt = fminf(fmaxf(p + pi_grad[i], 0.0f), 1.0f);
        ul += tgt * softplusf_(-s) + (1.0f - tgt) * softplusf_(s);
    }
    const f32x4* posv = reinterpret_cast<const f32x4*>(pos);
    for (int i = tid; i < POS_LEN / 4; i += stride) {
        f32x4 v = __builtin_nontemporal_load(posv + i);
        ps += softplusf_(-v[0]) + softplusf_(-v[1]) + softplusf_(-v[2]) + softplusf_(-v[3]);
    }
    const f32x4* negv = reinterpret_cast<const f32x4*>(neg);
    for (int i = tid; i < (POS_LEN * NUM_NEG) / 4; i += stride) {
        f32x4 v = __builtin_nontemporal_load(negv + i);
        ns += softplusf_(v[0]) + softplusf_(v[1]) + softplusf_(v[2]) + softplusf_(v[3]);
    }
    ul = wave_sum64(ul); ps = wave_sum64(ps); ns = wave_sum64(ns);
    __shared__ float lu[8], lp[8], ln[8];
    __shared__ bool last;
    const int lane = threadIdx.x & 63, wid = threadIdx.x >> 6;
    if (lane == 0) { lu[wid] = ul; lp[wid] = ps; ln[wid] = ns; }
    __syncthreads();
    if (threadIdx.x == 0) {
        float bu = 0.0f, bp = 0.0f, bn = 0.0f;
        for (int w = 0; w < (int)(blockDim.x >> 6); ++w) { bu += lu[w]; bp += lp[w]; bn += ln[w]; }
        lossp[blockIdx.x]                   = bu;
        lossp[LOSS_BLOCKS + blockIdx.x]     = bp;
        lossp[2 * LOSS_BLOCKS + blockIdx.x] = bn;
        __threadfence();                         // make partials visible device-wide
        unsigned prev = atomicAdd(done_count, 1u);
        last = (prev == LOSS_BLOCKS - 1);
    }
    __syncthreads();
    if (last && threadIdx.x < 64) {              // final reduction by one wave
        __threadfence();                         // acquire other blocks' partials
        const int fl = threadIdx.x;
        double sq = 0.0, tul = 0.0, tps = 0.0, tns = 0.0;
        for (int i = fl; i < AUX_BLOCKS; i += 64) sq += (double)auxp[i];
        for (int i = fl; i < LOSS_BLOCKS; i += 64) {
            tul += (double)lossp[i];
            tps += (double)lossp[LOSS_BLOCKS + i];
            tns += (double)lossp[2 * LOSS_BLOCKS + i];
        }
        sq = wave_sum64d(sq);   tul = wave_sum64d(tul);
        tps = wave_sum64d(tps); tns = wave_sum64d(tns);
        if (fl == 0) {
            double v = tps / (double)POS_LEN
                     + tns / ((double)POS_LEN * (double)NUM_NEG)
                     + tul / (double)N_UNLABEL
                     + WEIGHT_DECAY * sq;
            out[0] = (float)v;
        }
    }
}

extern "C" void kernel_launch(void* const* d_in, const int* in_sizes, int n_in,
                              void* d_out, int out_size, void* d_ws, size_t ws_size,
                              hipStream_t stream) {
    const float* pos  = (const float*)d_in[0];
    const float* neg  = (const float*)d_in[1];
    const float* conf = (const float*)d_in[2];
    const float* ent  = (const float*)d_in[3];
    const float* rel  = (const float*)d_in[4];
    const int*   p1   = (const int*)d_in[5];
    const int*   p2   = (const int*)d_in[6];
    const int*   tnum = (const int*)d_in[7];
    const int*   uids = (const int*)d_in[8];
    const int*   ut   = (const int*)d_in[9];

    // ws layout (all regions written unconditionally every call)
    const size_t off_pi    = 0;                                      // 512 KB
    const size_t off_su    = off_pi + (size_t)N_UNLABEL * 4;         // 512 KB
    const size_t off_auxp  = off_su + (size_t)N_UNLABEL * 4;         // 8 KB
    const size_t off_lossp = off_auxp + (size_t)AUX_BLOCKS * 4;      // 12 KB
    const size_t off_cnt   = off_lossp + (size_t)3 * LOSS_BLOCKS * 4;
    const size_t off_tab   = (off_cnt + 4 + 511) & ~(size_t)511;
    const size_t off_rel8  = off_tab + (size_t)NUM_ENT * EMB_DIM;    // fp8: 1 B/elem

    float*    pi_grad = (float*)((char*)d_ws + off_pi);
    float*    su      = (float*)((char*)d_ws + off_su);
    float*    auxp    = (float*)((char*)d_ws + off_auxp);
    float*    lossp   = (float*)((char*)d_ws + off_lossp);
    unsigned* cnt     = (unsigned*)((char*)d_ws + off_cnt);
    u32x2*    ent8w   = (u32x2*)((char*)d_ws + off_tab);
    u32x2*    rel8w   = (u32x2*)((char*)d_ws + off_rel8);

    aux_fp8_kernel<<<AUX_BLOCKS, 256, 0, stream>>>(ent, rel, ent8w, rel8w,
                                                   pi_grad, auxp, cnt);
    gather_kernel<<<GATHER_BLOCKS, 256, 0, stream>>>(conf,
                                                     (const u32x4*)((char*)d_ws + off_tab),
                                                     (const u32x4*)((char*)d_ws + off_rel8),
                                                     p1, p2, tnum, uids, ut, pi_grad, su);
    loss_kernel<<<LOSS_BLOCKS, 256, 0, stream>>>(su, pi_grad, pos, neg, auxp,
                                                 lossp, cnt, (float*)d_out);
}

// Round 10
// 94.710 us; speedup vs baseline: 1.3202x; 1.3202x over previous
//
#include <hip/hip_runtime.h>
#include <cstddef>
#include <cstdint>

#define POS_LEN    32768
#define NUM_NEG    64
#define N_RULES    262144
#define N_UNLABEL  131072
#define NUM_ENT    100000
#define NUM_REL    500
#define EMB_DIM    256
#define WEIGHT_DECAY 1e-5

#define AUX_BLOCKS    2048
#define GATHER_BLOCKS 2048
#define LOSS_BLOCKS   1024

typedef __attribute__((ext_vector_type(2))) float        f32x2;
typedef __attribute__((ext_vector_type(4))) float        f32x4;
typedef __attribute__((ext_vector_type(2))) unsigned int u32x2;
typedef __attribute__((ext_vector_type(4))) unsigned int u32x4;

__device__ __forceinline__ float softplusf_(float x) {
    return fmaxf(x, 0.0f) + log1pf(expf(-fabsf(x)));
}
__device__ __forceinline__ float sigmoidf_(float x) {
    return 1.0f / (1.0f + expf(-x));
}
__device__ __forceinline__ float quarter_sum16(float v) {   // reduce within 16-lane group
#pragma unroll
    for (int m = 1; m <= 8; m <<= 1) v += __shfl_xor(v, m, 64);
    return v;
}
__device__ __forceinline__ float wave_sum64(float v) {
#pragma unroll
    for (int m = 32; m >= 1; m >>= 1) v += __shfl_xor(v, m, 64);
    return v;
}
__device__ __forceinline__ double wave_sum64d(double v) {
#pragma unroll
    for (int m = 32; m >= 1; m >>= 1) v += __shfl_xor(v, m, 64);
    return v;
}

// ---- fp8 (OCP e4m3) pack/unpack via gfx950 HW converts (proven R4/R7) ----
__device__ __forceinline__ u32x2 f32x8_to_fp8(const f32x4 a, const f32x4 b) {
    int lo = 0, hi = 0;
    lo = __builtin_amdgcn_cvt_pk_fp8_f32(a[0], a[1], lo, false);
    lo = __builtin_amdgcn_cvt_pk_fp8_f32(a[2], a[3], lo, true);
    hi = __builtin_amdgcn_cvt_pk_fp8_f32(b[0], b[1], hi, false);
    hi = __builtin_amdgcn_cvt_pk_fp8_f32(b[2], b[3], hi, true);
    u32x2 r; r[0] = (unsigned)lo; r[1] = (unsigned)hi; return r;
}

// Quarter-wave tri-product over 16 fp8 elems/lane (16 lanes x 16 = 256 dims).
// float2-packed: compiler emits v_pk_mul_f32 / v_pk_fma_f32.
__device__ __forceinline__ float dot3_q(const u32x4 hv, const u32x4 rv, const u32x4 tv) {
    f32x2 acc = {0.0f, 0.0f};
#pragma unroll
    for (int w = 0; w < 4; ++w) {
        f32x2 h0 = __builtin_amdgcn_cvt_pk_f32_fp8((int)hv[w], false);
        f32x2 h1 = __builtin_amdgcn_cvt_pk_f32_fp8((int)hv[w], true);
        f32x2 r0 = __builtin_amdgcn_cvt_pk_f32_fp8((int)rv[w], false);
        f32x2 r1 = __builtin_amdgcn_cvt_pk_f32_fp8((int)rv[w], true);
        f32x2 t0 = __builtin_amdgcn_cvt_pk_f32_fp8((int)tv[w], false);
        f32x2 t1 = __builtin_amdgcn_cvt_pk_f32_fp8((int)tv[w], true);
        acc += (h0 * r0) * t0;
        acc += (h1 * r1) * t1;
    }
    return quarter_sum16(acc[0] + acc[1]);
}

// ---- Kernel 1: quantize ent/rel -> fp8, f32 sum-of-squares, zero pi_grad.
//      Per-block partial slots, no atomics. (Identical to R7/R9.) ----
__global__ __launch_bounds__(256) void aux_fp8_kernel(const float* __restrict__ ent,
                                                      const float* __restrict__ rel,
                                                      u32x2* __restrict__ ent8,
                                                      u32x2* __restrict__ rel8,
                                                      float* __restrict__ pi_grad,
                                                      float* __restrict__ auxp) {
    const int tid = blockIdx.x * blockDim.x + threadIdx.x;
    const int stride = gridDim.x * blockDim.x;
    for (int i = tid; i < N_UNLABEL; i += stride) pi_grad[i] = 0.0f;

    float sq = 0.0f;
    const f32x4* entv = reinterpret_cast<const f32x4*>(ent);
    for (int i = tid; i < (NUM_ENT * EMB_DIM) / 8; i += stride) {
        f32x4 a = __builtin_nontemporal_load(entv + (size_t)i * 2);
        f32x4 b = __builtin_nontemporal_load(entv + (size_t)i * 2 + 1);
        sq += a[0]*a[0] + a[1]*a[1] + a[2]*a[2] + a[3]*a[3]
            + b[0]*b[0] + b[1]*b[1] + b[2]*b[2] + b[3]*b[3];
        ent8[i] = f32x8_to_fp8(a, b);
    }
    const f32x4* relv = reinterpret_cast<const f32x4*>(rel);
    for (int i = tid; i < (NUM_REL * EMB_DIM) / 8; i += stride) {
        f32x4 a = __builtin_nontemporal_load(relv + (size_t)i * 2);
        f32x4 b = __builtin_nontemporal_load(relv + (size_t)i * 2 + 1);
        sq += a[0]*a[0] + a[1]*a[1] + a[2]*a[2] + a[3]*a[3]
            + b[0]*b[0] + b[1]*b[1] + b[2]*b[2] + b[3]*b[3];
        rel8[i] = f32x8_to_fp8(a, b);
    }
    sq = wave_sum64(sq);
    __shared__ float ls[8];
    const int lane = threadIdx.x & 63, wid = threadIdx.x >> 6;
    if (lane == 0) ls[wid] = sq;
    __syncthreads();
    if (threadIdx.x == 0) {
        float bs = 0.0f;
        for (int w = 0; w < (int)(blockDim.x >> 6); ++w) bs += ls[w];
        auxp[blockIdx.x] = bs;
    }
}

// ---- Kernel 2: fused fp8 gathers, quarter-wave (4 triples/wave), PAIRED
// iterations: each pass handles (pi, pi+nwave) so two rules' rows are in
// flight per wave (2x memory-level parallelism vs R7). ----
__global__ void gather_kernel(const float* __restrict__ conf,
                              const u32x4* __restrict__ ent8,
                              const u32x4* __restrict__ rel8,
                              const int* __restrict__ p1,
                              const int* __restrict__ p2,
                              const int* __restrict__ tnum,
                              const int* __restrict__ uids,
                              const int* __restrict__ ut,
                              float* __restrict__ pi_grad,
                              float* __restrict__ su_out) {
    const int lane = threadIdx.x & 63;
    const int l    = lane & 15;
    const int q    = lane >> 4;   // quarter 0..3
    const int wave  = blockIdx.x * (blockDim.x >> 6) + (threadIdx.x >> 6);
    const int nwave = gridDim.x * (blockDim.x >> 6);   // 8192 at this grid
    const int nr4 = N_RULES / 4, nu4 = N_UNLABEL / 4;

    // ---------- rules (nr4 = 65536 = 8 * nwave: pairs always in range) ----------
    for (int pi = wave; pi < nr4; pi += 2 * nwave) {
        const int pj = pi + nwave;
        const int ruleA = pi * 4 + q;
        const int ruleB = pj * 4 + q;
        const int ba = ruleA * 3, bb = ruleB * 3;
        // index/scalar loads for both rules
        const int hA1 = p1[ba], rA1 = p1[ba + 1], tA1 = p1[ba + 2];
        const int hB1 = p1[bb], rB1 = p1[bb + 1], tB1 = p1[bb + 2];
        const bool has2A = (tnum[ruleA] == 3);
        const bool has2B = (tnum[ruleB] == 3);
        const float cfA = conf[ruleA], cfB = conf[ruleB];
        const int uidA = uids[ruleA], uidB = uids[ruleB];
        // issue ALL row loads for both rules before any math
        const u32x4 HA1 = ent8[(size_t)hA1 * 16 + l];
        const u32x4 RA1 = rel8[(size_t)rA1 * 16 + l];
        const u32x4 TA1 = ent8[(size_t)tA1 * 16 + l];
        const u32x4 HB1 = ent8[(size_t)hB1 * 16 + l];
        const u32x4 RB1 = rel8[(size_t)rB1 * 16 + l];
        const u32x4 TB1 = ent8[(size_t)tB1 * 16 + l];
        u32x4 HA2 = {0,0,0,0}, RA2 = {0,0,0,0}, TA2 = {0,0,0,0};
        if (has2A) {
            HA2 = ent8[(size_t)p2[ba] * 16 + l];
            RA2 = rel8[(size_t)p2[ba + 1] * 16 + l];
            TA2 = ent8[(size_t)p2[ba + 2] * 16 + l];
        }
        u32x4 HB2 = {0,0,0,0}, RB2 = {0,0,0,0}, TB2 = {0,0,0,0};
        if (has2B) {
            HB2 = ent8[(size_t)p2[bb] * 16 + l];
            RB2 = rel8[(size_t)p2[bb + 1] * 16 + l];
            TB2 = ent8[(size_t)p2[bb + 2] * 16 + l];
        }
        // compute
        float cA = sigmoidf_(dot3_q(HA1, RA1, TA1)) * cfA;
        if (has2A) cA *= sigmoidf_(dot3_q(HA2, RA2, TA2));
        float cB = sigmoidf_(dot3_q(HB1, RB1, TB1)) * cfB;
        if (has2B) cB *= sigmoidf_(dot3_q(HB2, RB2, TB2));
        if (l == 0) {
            atomicAdd(&pi_grad[uidA], cA);
            atomicAdd(&pi_grad[uidB], cB);
        }
    }

    // ---------- unlabel (nu4 = 32768 = 4 * nwave: pairs always in range) ----------
    for (int pi = wave; pi < nu4; pi += 2 * nwave) {
        const int i0 = pi * 4 + q;
        const int i1 = (pi + nwave) * 4 + q;
        const int b0 = i0 * 3, b1 = i1 * 3;
        const int h0 = ut[b0], r0 = ut[b0 + 1], t0 = ut[b0 + 2];
        const int h1 = ut[b1], r1 = ut[b1 + 1], t1 = ut[b1 + 2];
        const u32x4 H0 = ent8[(size_t)h0 * 16 + l];
        const u32x4 R0 = rel8[(size_t)r0 * 16 + l];
        const u32x4 T0 = ent8[(size_t)t0 * 16 + l];
        const u32x4 H1 = ent8[(size_t)h1 * 16 + l];
        const u32x4 R1 = rel8[(size_t)r1 * 16 + l];
        const u32x4 T1 = ent8[(size_t)t1 * 16 + l];
        const float s0 = dot3_q(H0, R0, T0);
        const float s1 = dot3_q(H1, R1, T1);
        if (l == 0) {
            su_out[i0] = s0;
            su_out[i1] = s1;
        }
    }
}

// ---- Kernel 3: unlabel loss + pos/neg softplus sums. Per-block partials. ----
__global__ __launch_bounds__(256) void loss_kernel(const float* __restrict__ su,
                                                   const float* __restrict__ pi_grad,
                                                   const float* __restrict__ pos,
                                                   const float* __restrict__ neg,
                                                   float* __restrict__ lossp) {
    const int tid = blockIdx.x * blockDim.x + threadIdx.x;
    const int stride = gridDim.x * blockDim.x;
    float ul = 0.0f, ps = 0.0f, ns = 0.0f;
    for (int i = tid; i < N_UNLABEL; i += stride) {
        const float s   = su[i];
        const float p   = sigmoidf_(s);
        const float tgt = fminf(fmaxf(p + pi_grad[i], 0.0f), 1.0f);
        ul += tgt * softplusf_(-s) + (1.0f - tgt) * softplusf_(s);
    }
    const f32x4* posv = reinterpret_cast<const f32x4*>(pos);
    for (int i = tid; i < POS_LEN / 4; i += stride) {
        f32x4 v = __builtin_nontemporal_load(posv + i);
        ps += softplusf_(-v[0]) + softplusf_(-v[1]) + softplusf_(-v[2]) + softplusf_(-v[3]);
    }
    const f32x4* negv = reinterpret_cast<const f32x4*>(neg);
    for (int i = tid; i < (POS_LEN * NUM_NEG) / 4; i += stride) {
        f32x4 v = __builtin_nontemporal_load(negv + i);
        ns += softplusf_(v[0]) + softplusf_(v[1]) + softplusf_(v[2]) + softplusf_(v[3]);
    }
    ul = wave_sum64(ul); ps = wave_sum64(ps); ns = wave_sum64(ns);
    __shared__ float lu[8], lp[8], ln[8];
    const int lane = threadIdx.x & 63, wid = threadIdx.x >> 6;
    if (lane == 0) { lu[wid] = ul; lp[wid] = ps; ln[wid] = ns; }
    __syncthreads();
    if (threadIdx.x == 0) {
        float bu = 0.0f, bp = 0.0f, bn = 0.0f;
        for (int w = 0; w < (int)(blockDim.x >> 6); ++w) { bu += lu[w]; bp += lp[w]; bn += ln[w]; }
        lossp[blockIdx.x]                   = bu;
        lossp[LOSS_BLOCKS + blockIdx.x]     = bp;
        lossp[2 * LOSS_BLOCKS + blockIdx.x] = bn;
    }
}

// ---- Kernel 4: single-wave finalize in f64 (stream order provides sync). ----
__global__ void finalize_kernel(const float* __restrict__ auxp,
                                const float* __restrict__ lossp,
                                float* __restrict__ out) {
    const int lane = threadIdx.x;  // 64 threads
    double sq = 0.0, ul = 0.0, ps = 0.0, ns = 0.0;
    for (int i = lane; i < AUX_BLOCKS; i += 64) sq += (double)auxp[i];
    for (int i = lane; i < LOSS_BLOCKS; i += 64) {
        ul += (double)lossp[i];
        ps += (double)lossp[LOSS_BLOCKS + i];
        ns += (double)lossp[2 * LOSS_BLOCKS + i];
    }
    sq = wave_sum64d(sq); ul = wave_sum64d(ul);
    ps = wave_sum64d(ps); ns = wave_sum64d(ns);
    if (lane == 0) {
        double v = ps / (double)POS_LEN
                 + ns / ((double)POS_LEN * (double)NUM_NEG)
                 + ul / (double)N_UNLABEL
                 + WEIGHT_DECAY * sq;
        out[0] = (float)v;
    }
}

extern "C" void kernel_launch(void* const* d_in, const int* in_sizes, int n_in,
                              void* d_out, int out_size, void* d_ws, size_t ws_size,
                              hipStream_t stream) {
    const float* pos  = (const float*)d_in[0];
    const float* neg  = (const float*)d_in[1];
    const float* conf = (const float*)d_in[2];
    const float* ent  = (const float*)d_in[3];
    const float* rel  = (const float*)d_in[4];
    const int*   p1   = (const int*)d_in[5];
    const int*   p2   = (const int*)d_in[6];
    const int*   tnum = (const int*)d_in[7];
    const int*   uids = (const int*)d_in[8];
    const int*   ut   = (const int*)d_in[9];

    // ws layout (all regions written unconditionally every call)
    const size_t off_pi    = 0;                                      // 512 KB
    const size_t off_su    = off_pi + (size_t)N_UNLABEL * 4;         // 512 KB
    const size_t off_auxp  = off_su + (size_t)N_UNLABEL * 4;         // 8 KB
    const size_t off_lossp = off_auxp + (size_t)AUX_BLOCKS * 4;      // 12 KB
    const size_t off_tab   = (off_lossp + (size_t)3 * LOSS_BLOCKS * 4 + 511) & ~(size_t)511;
    const size_t off_rel8  = off_tab + (size_t)NUM_ENT * EMB_DIM;    // fp8: 1 B/elem

    float* pi_grad = (float*)((char*)d_ws + off_pi);
    float* su      = (float*)((char*)d_ws + off_su);
    float* auxp    = (float*)((char*)d_ws + off_auxp);
    float* lossp   = (float*)((char*)d_ws + off_lossp);
    u32x2* ent8w   = (u32x2*)((char*)d_ws + off_tab);
    u32x2* rel8w   = (u32x2*)((char*)d_ws + off_rel8);

    aux_fp8_kernel<<<AUX_BLOCKS, 256, 0, stream>>>(ent, rel, ent8w, rel8w, pi_grad, auxp);
    gather_kernel<<<GATHER_BLOCKS, 256, 0, stream>>>(conf,
                                                     (const u32x4*)((char*)d_ws + off_tab),
                                                     (const u32x4*)((char*)d_ws + off_rel8),
                                                     p1, p2, tnum, uids, ut, pi_grad, su);
    loss_kernel<<<LOSS_BLOCKS, 256, 0, stream>>>(su, pi_grad, pos, neg, lossp);
    finalize_kernel<<<1, 64, 0, stream>>>(auxp, lossp, (float*)d_out);
}